// Round 13
// baseline (205.976 us; speedup 1.0000x reference)
//
#include <hip/hip_runtime.h>
#include <math.h>

#define TPB 256
#define NBK_MAX 512   // max dst buckets (128 nodes each)
#define CAP 4096      // fixed e2/col region per bucket (mean 2046, sigma~45 -> 45-sigma)
#define FILL_CAP 4096 // LDS col-buffer per bucket (== CAP)
#define SC_CH 16      // register-held edges per thread in bscatter

typedef short bf16x8 __attribute__((ext_vector_type(8)));
typedef float f32x4 __attribute__((ext_vector_type(4)));

__device__ __forceinline__ unsigned short rne_bf16(float f) {
  unsigned u = __float_as_uint(f);
  return (unsigned short)((u + 0x7fffu + ((u >> 16) & 1u)) >> 16);
}
__device__ __forceinline__ float bf16_f(unsigned short v) {
  return __uint_as_float((unsigned)v << 16);
}
// fast tanh: (e-1)*rcp(e+1), e=exp(2x), x clamped to +-15; abs err ~1e-7.
__device__ __forceinline__ float ftanh(float x) {
  float xc = fminf(fmaxf(x, -15.f), 15.f);
  float e = __expf(2.f * xc);
  return (e - 1.f) * __builtin_amdgcn_rcpf(e + 1.f);
}

// ---------------- init: bucket cursors to fixed region starts ----------------
__global__ __launch_bounds__(TPB) void k_init(int* __restrict__ gcur, int NBK) {
  int i = blockIdx.x * TPB + threadIdx.x;
  if (i < NBK) gcur[i] = i * CAP;
}

// ---------------- scatter edges into fixed-capacity bucket regions of e2 ----------------
// Per-tile LDS histogram -> one atomic range-reservation per bucket -> ranked
// scatter. Each reserved range is contiguous & single-block-written (no
// cross-XCD line ping-pong). Reservation clamped to stay in-region.
__global__ __launch_bounds__(TPB) void k_bscatter(const int* __restrict__ src,
                                                  const int* __restrict__ dst,
                                                  int* __restrict__ gcur,
                                                  unsigned* __restrict__ e2,
                                                  int E, int NBK) {
  __shared__ int h[NBK_MAX];
  __shared__ int base[NBK_MAX];
  int tid = threadIdx.x, blk = blockIdx.x, G = gridDim.x;
  int chunk = (E + G - 1) / G, lo = blk * chunk, hi = min(E, lo + chunk);
  for (int t0 = lo; t0 < hi; t0 += TPB * SC_CH) {
    int sv[SC_CH], dv[SC_CH];
    for (int b = tid; b < NBK; b += TPB) h[b] = 0;
    __syncthreads();
#pragma unroll
    for (int u = 0; u < SC_CH; ++u) {
      int e = t0 + u * TPB + tid;
      if (e < hi) {
        dv[u] = dst[e];
        sv[u] = src[e];
        atomicAdd(&h[dv[u] >> 7], 1);
      } else {
        dv[u] = -1;
      }
    }
    __syncthreads();
    for (int b = tid; b < NBK; b += TPB) {
      int c = h[b];
      if (c) {
        int o = atomicAdd(&gcur[b], c);
        base[b] = min(o, (b + 1) * CAP - c);  // never escapes the region
      }
    }
    __syncthreads();
    for (int b = tid; b < NBK; b += TPB) h[b] = 0;
    __syncthreads();
#pragma unroll
    for (int u = 0; u < SC_CH; ++u) {
      if (dv[u] >= 0) {
        int bk = dv[u] >> 7;
        int r = atomicAdd(&h[bk], 1);
        e2[base[bk] + r] = ((unsigned)sv[u] << 7) | (unsigned)(dv[u] & 127);
      }
    }
    __syncthreads();
  }
}

// ---------------- per-bucket count/scan/rowptr/rowend/dinv + CSR fill ----------------
// Bucket b region = [b*CAP, gcur[b]) in e2; col uses the same padded layout, so
// rowptr/rowend are per-node absolute pointers (buckets not globally contiguous).
__global__ __launch_bounds__(TPB) void k_build(const unsigned* __restrict__ e2,
                                               const int* __restrict__ gcur,
                                               int* __restrict__ rowptr,
                                               int* __restrict__ rowend,
                                               float* __restrict__ dinv,
                                               int* __restrict__ col, int N) {
  __shared__ int c[128], sc[128], cur[128];
  __shared__ int buf[FILL_CAP];
  int tid = threadIdx.x, b = blockIdx.x;
  int st = b * CAP;
  int en = min(gcur[b], st + FILL_CAP);
  int len = en - st;
  if (tid < 128) c[tid] = 0;
  __syncthreads();
  for (int i = st + tid; i < en; i += TPB) atomicAdd(&c[e2[i] & 127u], 1);
  __syncthreads();
  if (tid < 128) sc[tid] = c[tid];
  __syncthreads();
  for (int o = 1; o < 128; o <<= 1) {
    int v = (tid >= o && tid < 128) ? sc[tid - o] : 0;
    __syncthreads();
    if (tid < 128) sc[tid] += v;
    __syncthreads();
  }
  if (tid < 128) {
    int excl = sc[tid] - c[tid];
    cur[tid] = excl;
    int node = b * 128 + tid;
    if (node < N) {
      rowptr[node] = st + excl;
      rowend[node] = st + excl + c[tid];
      dinv[node] = rsqrtf((float)(c[tid] + 1));  // +1 self-loop
    }
  }
  __syncthreads();
  for (int i = st + tid; i < en; i += TPB) {
    unsigned v = e2[i];
    int p = atomicAdd(&cur[v & 127u], 1);
    buf[p] = (int)(v >> 7);
  }
  __syncthreads();
  for (int i = tid; i < len; i += TPB) col[st + i] = buf[i];
}

// ---------------- MFMA GEMM with in-kernel W split; dinv-prescaled fp32 output ----------------
// Hout[row] = (A @ W)[row] * dinv[row]  (fp32, unrounded) -- GCN norm factored
// out of the edge loop: out[d] = dinv[d] * (sum_s H'[s] + H'[d]), H' = dinv*H.
template <int K>
__global__ __launch_bounds__(TPB) void k_mm(const float* __restrict__ Ap,
                                            const float* __restrict__ W,
                                            const float* __restrict__ dinv,
                                            float* __restrict__ Hout, int N) {
  constexpr int P = K + 8;  // LDS pitch: conflict-free b128 frag reads
  __shared__ unsigned short sHi[64 * P];
  __shared__ unsigned short sLo[64 * P];
  int tid = threadIdx.x;
  // stage + transpose + split: W[k][n] fp32 -> sHi/sLo[n][k] bf16
  for (int i = tid; i < K * 64; i += TPB) {
    int k = i >> 6, n = i & 63;  // coalesced read of W
    float w = W[i];
    unsigned short hb = rne_bf16(w);
    sHi[n * P + k] = hb;
    sLo[n * P + k] = rne_bf16(w - bf16_f(hb));
  }
  __syncthreads();
  int wave = tid >> 6, lane = tid & 63;
  int oct = lane >> 4, l15 = lane & 15;
  int base = blockIdx.x * 64 + wave * 16;
  int arow = base + l15;
  if (arow >= N) arow = N - 1;
  f32x4 acc[4] = {};
#pragma unroll
  for (int s = 0; s < K / 32; ++s) {
    bf16x8 ahi, alo;
    const float* ap = Ap + (size_t)arow * K + s * 32 + oct * 8;
    float4 f0 = *(const float4*)ap;
    float4 f1 = *(const float4*)(ap + 4);
    float fv[8] = {f0.x, f0.y, f0.z, f0.w, f1.x, f1.y, f1.z, f1.w};
#pragma unroll
    for (int j = 0; j < 8; ++j) {
      unsigned short hb = rne_bf16(fv[j]);
      ahi[j] = (short)hb;
      alo[j] = (short)rne_bf16(fv[j] - bf16_f(hb));
    }
#pragma unroll
    for (int t = 0; t < 4; ++t) {
      bf16x8 bh = *(const bf16x8*)(sHi + (t * 16 + l15) * P + s * 32 + oct * 8);
      bf16x8 bl = *(const bf16x8*)(sLo + (t * 16 + l15) * P + s * 32 + oct * 8);
      acc[t] = __builtin_amdgcn_mfma_f32_16x16x32_bf16(ahi, bh, acc[t], 0, 0, 0);
      acc[t] = __builtin_amdgcn_mfma_f32_16x16x32_bf16(ahi, bl, acc[t], 0, 0, 0);
      acc[t] = __builtin_amdgcn_mfma_f32_16x16x32_bf16(alo, bh, acc[t], 0, 0, 0);
    }
  }
#pragma unroll
  for (int r = 0; r < 4; ++r) {
    int row = base + oct * 4 + r;
    if (row < N) {
      float dv = dinv[row];  // same addr across l15 lanes -> broadcast
#pragma unroll
      for (int t = 0; t < 4; ++t)
        Hout[(size_t)row * 64 + t * 16 + l15] = acc[t][r] * dv;
    }
  }
}

// ---------------- per-node aggregation body (fp32 H, lane = feature) ----------------
// Wave sums pre-scaled fp32 rows of node i's neighbors + self. Edge index is
// WAVE-UNIFORM per load (v_readlane -> SGPR), so the gather address computes on
// SALU (free) and the load is saddr-form with lane*4 offset: per edge cost =
// 1 readlane + 1 load + 1 v_add_f32. Exact-length tail (no padded slots).
__device__ __forceinline__ float agg_node(int i, const float* __restrict__ H,
                                          const int* __restrict__ rowptr,
                                          const int* __restrict__ rowend,
                                          const int* __restrict__ col) {
  int lane = threadIdx.x & 63;
  float acc = H[((size_t)i << 6) + lane];  // self-loop
  int beg = rowptr[i], end = rowend[i];
  for (int c0 = beg; c0 < end; c0 += 64) {
    int jj = c0 + lane;
    int sv = col[(jj < end) ? jj : beg];  // lanes >= lim never used
    int lim = min(64, end - c0);
    int t = 0;
    for (; t + 8 <= lim; t += 8) {
      int s0 = __builtin_amdgcn_readlane(sv, t + 0);
      int s1 = __builtin_amdgcn_readlane(sv, t + 1);
      int s2 = __builtin_amdgcn_readlane(sv, t + 2);
      int s3 = __builtin_amdgcn_readlane(sv, t + 3);
      int s4 = __builtin_amdgcn_readlane(sv, t + 4);
      int s5 = __builtin_amdgcn_readlane(sv, t + 5);
      int s6 = __builtin_amdgcn_readlane(sv, t + 6);
      int s7 = __builtin_amdgcn_readlane(sv, t + 7);
      float h0 = H[((size_t)s0 << 6) + lane];
      float h1 = H[((size_t)s1 << 6) + lane];
      float h2 = H[((size_t)s2 << 6) + lane];
      float h3 = H[((size_t)s3 << 6) + lane];
      float h4 = H[((size_t)s4 << 6) + lane];
      float h5 = H[((size_t)s5 << 6) + lane];
      float h6 = H[((size_t)s6 << 6) + lane];
      float h7 = H[((size_t)s7 << 6) + lane];
      acc += h0; acc += h1; acc += h2; acc += h3;
      acc += h4; acc += h5; acc += h6; acc += h7;
    }
    if (t + 4 <= lim) {
      int s0 = __builtin_amdgcn_readlane(sv, t + 0);
      int s1 = __builtin_amdgcn_readlane(sv, t + 1);
      int s2 = __builtin_amdgcn_readlane(sv, t + 2);
      int s3 = __builtin_amdgcn_readlane(sv, t + 3);
      float h0 = H[((size_t)s0 << 6) + lane];
      float h1 = H[((size_t)s1 << 6) + lane];
      float h2 = H[((size_t)s2 << 6) + lane];
      float h3 = H[((size_t)s3 << 6) + lane];
      acc += h0; acc += h1; acc += h2; acc += h3;
      t += 4;
    }
    for (; t < lim; ++t) {
      int s = __builtin_amdgcn_readlane(sv, t);
      acc += H[((size_t)s << 6) + lane];
    }
  }
  return acc;
}

// ---------------- aggregation kernel; DOFC fuses the MLP head ----------------
// FC LDS layout: sw1t pitch 66 floats (2-way bank aliasing = free [m136]).
template <bool DOFC>
__global__ __launch_bounds__(TPB) void k_agg(const float* __restrict__ H,
                                             const int* __restrict__ rowptr,
                                             const int* __restrict__ rowend,
                                             const int* __restrict__ col,
                                             const float* __restrict__ dinv,
                                             const float* __restrict__ bias,
                                             float* __restrict__ OUT,
                                             const float* __restrict__ fw1,
                                             const float* __restrict__ fb1,
                                             const float* __restrict__ fw2,
                                             const float* __restrict__ fb2,
                                             float* __restrict__ fout, int N) {
  int tid = threadIdx.x;
  int wid = tid >> 6, lane = tid & 63;
  float bfeat = bias[lane];
  if constexpr (!DOFC) {
    int i = (blockIdx.x * TPB + tid) >> 6;
    if (i >= N) return;
    float v = agg_node(i, H, rowptr, rowend, col);
    OUT[((size_t)i << 6) + lane] = ftanh(dinv[i] * v + bfeat);
  } else {
    __shared__ float sw1t[32 * 66];  // [j][k] pitch 66 (conflict-free)
    __shared__ float sb1[32];
    __shared__ float sw2[32];
    __shared__ float sA[4 * 64];
    for (int i = tid; i < 32 * 64; i += TPB) {
      int j = i >> 6, k = i & 63;
      sw1t[j * 66 + k] = fw1[k * 32 + j];
    }
    if (tid < 32) { sb1[tid] = fb1[tid]; sw2[tid] = fw2[tid]; }
    __syncthreads();
    int ngroups = (N + 3) / 4;
    float b2v = fb2[0];
    for (int grp = blockIdx.x; grp < ngroups; grp += gridDim.x) {
      int i = grp * 4 + wid;
      float v = 0.f, di = 0.f;
      if (i < N) {
        di = dinv[i];
        v = agg_node(i, H, rowptr, rowend, col);
      }
      sA[wid * 64 + lane] = ftanh(di * v + bfeat);
      __syncthreads();
      if (tid < 128) {
        int n = tid >> 5, j = tid & 31;
        int node = grp * 4 + n;
        if (node < N) {
          float acc = sb1[j];
          const float2* ar = (const float2*)(sA + n * 64);     // broadcast reads
          const float2* wr = (const float2*)(sw1t + j * 66);   // 2-way (free)
#pragma unroll
          for (int k2 = 0; k2 < 32; ++k2) {
            float2 av = ar[k2];
            float2 wv = wr[k2];
            acc += av.x * wv.x + av.y * wv.y;
          }
          float t = ftanh(acc) * sw2[j];
#pragma unroll
          for (int o = 1; o < 32; o <<= 1) t += __shfl_xor(t, o);
          if (j == 0) fout[node] = t + b2v;
        }
      }
      __syncthreads();
    }
  }
}

// ================= host =================

extern "C" void kernel_launch(void* const* d_in, const int* in_sizes, int n_in,
                              void* d_out, int out_size, void* d_ws, size_t ws_size,
                              hipStream_t stream) {
  const float* x   = (const float*)d_in[0];
  const int*   ei  = (const int*)d_in[1];
  const float* w1  = (const float*)d_in[2];
  const float* b1  = (const float*)d_in[3];
  const float* w2  = (const float*)d_in[4];
  const float* b2  = (const float*)d_in[5];
  const float* fw1 = (const float*)d_in[6];
  const float* fb1 = (const float*)d_in[7];
  const float* fw2 = (const float*)d_in[8];
  const float* fb2 = (const float*)d_in[9];
  float* out = (float*)d_out;

  int N = in_sizes[0] / 128;
  int E = in_sizes[1] / 2;
  const int* src = ei;
  const int* dst = ei + E;

  const int G   = 256;                // blocks for the edge scatter (write locality)
  const int NBK = (N + 127) / 128;    // 391 buckets

  char* p = (char*)d_ws;
  size_t off = 0;
  auto take = [&](size_t bytes) -> void* {
    void* r = p + off;
    off += (bytes + 255) & ~(size_t)255;
    return r;
  };
  int*      gcur   = (int*)take((size_t)NBK * 4);
  int*      rowptr = (int*)take((size_t)N * 4);
  int*      rowend = (int*)take((size_t)N * 4);
  float*    dinv   = (float*)take((size_t)N * 4);
  unsigned* e2     = (unsigned*)take((size_t)NBK * CAP * 4);
  int*      col    = (int*)take((size_t)NBK * CAP * 4);
  float*    h      = (float*)take((size_t)N * 64 * 4);
  float*    a      = (float*)take((size_t)N * 64 * 4);
  (void)ws_size; (void)n_in; (void)out_size;

  // graph build: 3 kernels (fixed-capacity buckets -> no count/scan pre-pass)
  k_init<<<(NBK + TPB - 1) / TPB, TPB, 0, stream>>>(gcur, NBK);
  k_bscatter<<<G, TPB, 0, stream>>>(src, dst, gcur, e2, E, NBK);
  k_build<<<NBK, TPB, 0, stream>>>(e2, gcur, rowptr, rowend, dinv, col, N);

  // network (H rows pre-scaled by dinv in the mm epilogues, kept fp32)
  int gmm = (N + 63) / 64;
  k_mm<128><<<gmm, TPB, 0, stream>>>(x, w1, dinv, h, N);
  k_agg<false><<<(N + 3) / 4, TPB, 0, stream>>>(h, rowptr, rowend, col, dinv, b1, a,
                                                nullptr, nullptr, nullptr, nullptr,
                                                nullptr, N);
  k_mm<64><<<gmm, TPB, 0, stream>>>(a, w2, dinv, h, N);
  k_agg<true><<<4096, TPB, 0, stream>>>(h, rowptr, rowend, col, dinv, b2, nullptr,
                                        fw1, fb1, fw2, fb2, out, N);
}

// Round 14
// 193.443 us; speedup vs baseline: 1.0648x; 1.0648x over previous
//
#include <hip/hip_runtime.h>
#include <math.h>

#define TPB 256
#define NBK_MAX 512   // max dst buckets (128 nodes each)
#define CAP 4096      // fixed e2/col region per bucket (mean 2046, sigma~45 -> 45-sigma)
#define FILL_CAP 4096 // LDS col-buffer per bucket (== CAP)
#define SC_CH 16      // register-held edges per thread in bscatter

typedef short bf16x8 __attribute__((ext_vector_type(8)));
typedef float f32x4 __attribute__((ext_vector_type(4)));

__device__ __forceinline__ unsigned short rne_bf16(float f) {
  unsigned u = __float_as_uint(f);
  return (unsigned short)((u + 0x7fffu + ((u >> 16) & 1u)) >> 16);
}
__device__ __forceinline__ float bf16_f(unsigned short v) {
  return __uint_as_float((unsigned)v << 16);
}
// fast tanh: (e-1)*rcp(e+1), e=exp(2x), x clamped to +-15; abs err ~1e-7.
__device__ __forceinline__ float ftanh(float x) {
  float xc = fminf(fmaxf(x, -15.f), 15.f);
  float e = __expf(2.f * xc);
  return (e - 1.f) * __builtin_amdgcn_rcpf(e + 1.f);
}

// ---------------- init: bucket cursors to fixed region starts ----------------
__global__ __launch_bounds__(TPB) void k_init(int* __restrict__ gcur, int NBK) {
  int i = blockIdx.x * TPB + threadIdx.x;
  if (i < NBK) gcur[i] = i * CAP;
}

// ---------------- scatter edges into fixed-capacity bucket regions of e2 ----------------
// Per-tile LDS histogram -> one atomic range-reservation per bucket -> ranked
// scatter. Each reserved range is contiguous & single-block-written (no
// cross-XCD line ping-pong). Reservation clamped to stay in-region.
__global__ __launch_bounds__(TPB) void k_bscatter(const int* __restrict__ src,
                                                  const int* __restrict__ dst,
                                                  int* __restrict__ gcur,
                                                  unsigned* __restrict__ e2,
                                                  int E, int NBK) {
  __shared__ int h[NBK_MAX];
  __shared__ int base[NBK_MAX];
  int tid = threadIdx.x, blk = blockIdx.x, G = gridDim.x;
  int chunk = (E + G - 1) / G, lo = blk * chunk, hi = min(E, lo + chunk);
  for (int t0 = lo; t0 < hi; t0 += TPB * SC_CH) {
    int sv[SC_CH], dv[SC_CH];
    for (int b = tid; b < NBK; b += TPB) h[b] = 0;
    __syncthreads();
#pragma unroll
    for (int u = 0; u < SC_CH; ++u) {
      int e = t0 + u * TPB + tid;
      if (e < hi) {
        dv[u] = dst[e];
        sv[u] = src[e];
        atomicAdd(&h[dv[u] >> 7], 1);
      } else {
        dv[u] = -1;
      }
    }
    __syncthreads();
    for (int b = tid; b < NBK; b += TPB) {
      int c = h[b];
      if (c) {
        int o = atomicAdd(&gcur[b], c);
        base[b] = min(o, (b + 1) * CAP - c);  // never escapes the region
      }
    }
    __syncthreads();
    for (int b = tid; b < NBK; b += TPB) h[b] = 0;
    __syncthreads();
#pragma unroll
    for (int u = 0; u < SC_CH; ++u) {
      if (dv[u] >= 0) {
        int bk = dv[u] >> 7;
        int r = atomicAdd(&h[bk], 1);
        e2[base[bk] + r] = ((unsigned)sv[u] << 7) | (unsigned)(dv[u] & 127);
      }
    }
    __syncthreads();
  }
}

// ---------------- per-bucket count/scan/rowptr/rowend/dinv + CSR fill ----------------
// Bucket b region = [b*CAP, gcur[b]) in e2; col uses the same padded layout, so
// rowptr/rowend are per-node absolute pointers (buckets not globally contiguous).
__global__ __launch_bounds__(TPB) void k_build(const unsigned* __restrict__ e2,
                                               const int* __restrict__ gcur,
                                               int* __restrict__ rowptr,
                                               int* __restrict__ rowend,
                                               float* __restrict__ dinv,
                                               int* __restrict__ col, int N) {
  __shared__ int c[128], sc[128], cur[128];
  __shared__ int buf[FILL_CAP];
  int tid = threadIdx.x, b = blockIdx.x;
  int st = b * CAP;
  int en = min(gcur[b], st + FILL_CAP);
  int len = en - st;
  if (tid < 128) c[tid] = 0;
  __syncthreads();
  for (int i = st + tid; i < en; i += TPB) atomicAdd(&c[e2[i] & 127u], 1);
  __syncthreads();
  if (tid < 128) sc[tid] = c[tid];
  __syncthreads();
  for (int o = 1; o < 128; o <<= 1) {
    int v = (tid >= o && tid < 128) ? sc[tid - o] : 0;
    __syncthreads();
    if (tid < 128) sc[tid] += v;
    __syncthreads();
  }
  if (tid < 128) {
    int excl = sc[tid] - c[tid];
    cur[tid] = excl;
    int node = b * 128 + tid;
    if (node < N) {
      rowptr[node] = st + excl;
      rowend[node] = st + excl + c[tid];
      dinv[node] = rsqrtf((float)(c[tid] + 1));  // +1 self-loop
    }
  }
  __syncthreads();
  for (int i = st + tid; i < en; i += TPB) {
    unsigned v = e2[i];
    int p = atomicAdd(&cur[v & 127u], 1);
    buf[p] = (int)(v >> 7);
  }
  __syncthreads();
  for (int i = tid; i < len; i += TPB) col[st + i] = buf[i];
}

// ---------------- MFMA GEMM with in-kernel W split; dinv-prescaled bf16 output ----------------
// Hout[row] = rne_bf16( (A @ W)[row] * dinv[row] ) -- GCN norm factored out of
// the edge loop: out[d] = dinv[d] * (sum_s H'[s] + H'[d]), H' = dinv*H.
template <int K, bool AF32>
__global__ __launch_bounds__(TPB) void k_mm(const void* __restrict__ Ap,
                                            const float* __restrict__ W,
                                            const float* __restrict__ dinv,
                                            unsigned short* __restrict__ Hout, int N) {
  constexpr int P = K + 8;  // LDS pitch: conflict-free b128 frag reads
  __shared__ unsigned short sHi[64 * P];
  __shared__ unsigned short sLo[64 * P];
  int tid = threadIdx.x;
  // stage + transpose + split: W[k][n] fp32 -> sHi/sLo[n][k] bf16
  for (int i = tid; i < K * 64; i += TPB) {
    int k = i >> 6, n = i & 63;  // coalesced read of W
    float w = W[i];
    unsigned short hb = rne_bf16(w);
    sHi[n * P + k] = hb;
    sLo[n * P + k] = rne_bf16(w - bf16_f(hb));
  }
  __syncthreads();
  int wave = tid >> 6, lane = tid & 63;
  int oct = lane >> 4, l15 = lane & 15;
  int base = blockIdx.x * 64 + wave * 16;
  int arow = base + l15;
  if (arow >= N) arow = N - 1;
  f32x4 acc[4] = {};
#pragma unroll
  for (int s = 0; s < K / 32; ++s) {
    bf16x8 ahi, alo;
    if (AF32) {
      const float* ap = (const float*)Ap + (size_t)arow * K + s * 32 + oct * 8;
      float4 f0 = *(const float4*)ap;
      float4 f1 = *(const float4*)(ap + 4);
      float fv[8] = {f0.x, f0.y, f0.z, f0.w, f1.x, f1.y, f1.z, f1.w};
#pragma unroll
      for (int j = 0; j < 8; ++j) {
        unsigned short hb = rne_bf16(fv[j]);
        ahi[j] = (short)hb;
        alo[j] = (short)rne_bf16(fv[j] - bf16_f(hb));
      }
    } else {
      ahi = *(const bf16x8*)((const unsigned short*)Ap + (size_t)arow * K + s * 32 + oct * 8);
    }
#pragma unroll
    for (int t = 0; t < 4; ++t) {
      bf16x8 bh = *(const bf16x8*)(sHi + (t * 16 + l15) * P + s * 32 + oct * 8);
      bf16x8 bl = *(const bf16x8*)(sLo + (t * 16 + l15) * P + s * 32 + oct * 8);
      acc[t] = __builtin_amdgcn_mfma_f32_16x16x32_bf16(ahi, bh, acc[t], 0, 0, 0);
      acc[t] = __builtin_amdgcn_mfma_f32_16x16x32_bf16(ahi, bl, acc[t], 0, 0, 0);
      if (AF32)
        acc[t] = __builtin_amdgcn_mfma_f32_16x16x32_bf16(alo, bh, acc[t], 0, 0, 0);
    }
  }
#pragma unroll
  for (int r = 0; r < 4; ++r) {
    int row = base + oct * 4 + r;
    if (row < N) {
      float dv = dinv[row];  // same addr across l15 lanes -> broadcast
#pragma unroll
      for (int t = 0; t < 4; ++t)
        Hout[(size_t)row * 64 + t * 16 + l15] = rne_bf16(acc[t][r] * dv);
    }
  }
}

// ---------------- per-node aggregation body (bf16 H, lane = feature) ----------------
// Wave sums pre-scaled bf16 rows of node i's neighbors + self. Edge index is
// WAVE-UNIFORM per load (v_readlane -> SGPR): gather address computes on SALU
// and the ushort load is saddr-form with lane*2 offset. Per edge: 1 readlane +
// 1 load_ushort + 1 lshl + 1 add. All 64 lanes active on every edge (no tail
// padding, no sentinel). bf16 rows keep the L2-miss traffic at R12's ~33 MB.
__device__ __forceinline__ float agg_node(int i, const unsigned short* __restrict__ H,
                                          const int* __restrict__ rowptr,
                                          const int* __restrict__ rowend,
                                          const int* __restrict__ col) {
  int lane = threadIdx.x & 63;
  float acc = bf16_f(H[((size_t)i << 6) + lane]);  // self-loop
  int beg = rowptr[i], end = rowend[i];
  for (int c0 = beg; c0 < end; c0 += 64) {
    int jj = c0 + lane;
    int sv = col[(jj < end) ? jj : beg];  // lanes >= lim never used
    int lim = min(64, end - c0);
    int t = 0;
    for (; t + 8 <= lim; t += 8) {
      int s0 = __builtin_amdgcn_readlane(sv, t + 0);
      int s1 = __builtin_amdgcn_readlane(sv, t + 1);
      int s2 = __builtin_amdgcn_readlane(sv, t + 2);
      int s3 = __builtin_amdgcn_readlane(sv, t + 3);
      int s4 = __builtin_amdgcn_readlane(sv, t + 4);
      int s5 = __builtin_amdgcn_readlane(sv, t + 5);
      int s6 = __builtin_amdgcn_readlane(sv, t + 6);
      int s7 = __builtin_amdgcn_readlane(sv, t + 7);
      unsigned short h0 = H[((size_t)s0 << 6) + lane];
      unsigned short h1 = H[((size_t)s1 << 6) + lane];
      unsigned short h2 = H[((size_t)s2 << 6) + lane];
      unsigned short h3 = H[((size_t)s3 << 6) + lane];
      unsigned short h4 = H[((size_t)s4 << 6) + lane];
      unsigned short h5 = H[((size_t)s5 << 6) + lane];
      unsigned short h6 = H[((size_t)s6 << 6) + lane];
      unsigned short h7 = H[((size_t)s7 << 6) + lane];
      acc += bf16_f(h0); acc += bf16_f(h1); acc += bf16_f(h2); acc += bf16_f(h3);
      acc += bf16_f(h4); acc += bf16_f(h5); acc += bf16_f(h6); acc += bf16_f(h7);
    }
    if (t + 4 <= lim) {
      int s0 = __builtin_amdgcn_readlane(sv, t + 0);
      int s1 = __builtin_amdgcn_readlane(sv, t + 1);
      int s2 = __builtin_amdgcn_readlane(sv, t + 2);
      int s3 = __builtin_amdgcn_readlane(sv, t + 3);
      unsigned short h0 = H[((size_t)s0 << 6) + lane];
      unsigned short h1 = H[((size_t)s1 << 6) + lane];
      unsigned short h2 = H[((size_t)s2 << 6) + lane];
      unsigned short h3 = H[((size_t)s3 << 6) + lane];
      acc += bf16_f(h0); acc += bf16_f(h1); acc += bf16_f(h2); acc += bf16_f(h3);
      t += 4;
    }
    for (; t < lim; ++t) {
      int s = __builtin_amdgcn_readlane(sv, t);
      acc += bf16_f(H[((size_t)s << 6) + lane]);
    }
  }
  return acc;
}

// ---------------- aggregation kernel; DOFC fuses the MLP head ----------------
// FC LDS layout: sw1t pitch 66 floats (2-way bank aliasing = free [m136]).
template <bool DOFC>
__global__ __launch_bounds__(TPB) void k_agg(const unsigned short* __restrict__ H,
                                             const int* __restrict__ rowptr,
                                             const int* __restrict__ rowend,
                                             const int* __restrict__ col,
                                             const float* __restrict__ dinv,
                                             const float* __restrict__ bias,
                                             unsigned short* __restrict__ OUT,
                                             const float* __restrict__ fw1,
                                             const float* __restrict__ fb1,
                                             const float* __restrict__ fw2,
                                             const float* __restrict__ fb2,
                                             float* __restrict__ fout, int N) {
  int tid = threadIdx.x;
  int wid = tid >> 6, lane = tid & 63;
  float bfeat = bias[lane];
  if constexpr (!DOFC) {
    int i = (blockIdx.x * TPB + tid) >> 6;
    if (i >= N) return;
    float v = agg_node(i, H, rowptr, rowend, col);
    OUT[((size_t)i << 6) + lane] = rne_bf16(ftanh(dinv[i] * v + bfeat));
  } else {
    __shared__ float sw1t[32 * 66];  // [j][k] pitch 66 (conflict-free)
    __shared__ float sb1[32];
    __shared__ float sw2[32];
    __shared__ float sA[4 * 64];
    for (int i = tid; i < 32 * 64; i += TPB) {
      int j = i >> 6, k = i & 63;
      sw1t[j * 66 + k] = fw1[k * 32 + j];
    }
    if (tid < 32) { sb1[tid] = fb1[tid]; sw2[tid] = fw2[tid]; }
    __syncthreads();
    int ngroups = (N + 3) / 4;
    float b2v = fb2[0];
    for (int grp = blockIdx.x; grp < ngroups; grp += gridDim.x) {
      int i = grp * 4 + wid;
      float v = 0.f, di = 0.f;
      if (i < N) {
        di = dinv[i];
        v = agg_node(i, H, rowptr, rowend, col);
      }
      sA[wid * 64 + lane] = ftanh(di * v + bfeat);
      __syncthreads();
      if (tid < 128) {
        int n = tid >> 5, j = tid & 31;
        int node = grp * 4 + n;
        if (node < N) {
          float acc = sb1[j];
          const float2* ar = (const float2*)(sA + n * 64);     // broadcast reads
          const float2* wr = (const float2*)(sw1t + j * 66);   // 2-way (free)
#pragma unroll
          for (int k2 = 0; k2 < 32; ++k2) {
            float2 av = ar[k2];
            float2 wv = wr[k2];
            acc += av.x * wv.x + av.y * wv.y;
          }
          float t = ftanh(acc) * sw2[j];
#pragma unroll
          for (int o = 1; o < 32; o <<= 1) t += __shfl_xor(t, o);
          if (j == 0) fout[node] = t + b2v;
        }
      }
      __syncthreads();
    }
  }
}

// ================= host =================

extern "C" void kernel_launch(void* const* d_in, const int* in_sizes, int n_in,
                              void* d_out, int out_size, void* d_ws, size_t ws_size,
                              hipStream_t stream) {
  const float* x   = (const float*)d_in[0];
  const int*   ei  = (const int*)d_in[1];
  const float* w1  = (const float*)d_in[2];
  const float* b1  = (const float*)d_in[3];
  const float* w2  = (const float*)d_in[4];
  const float* b2  = (const float*)d_in[5];
  const float* fw1 = (const float*)d_in[6];
  const float* fb1 = (const float*)d_in[7];
  const float* fw2 = (const float*)d_in[8];
  const float* fb2 = (const float*)d_in[9];
  float* out = (float*)d_out;

  int N = in_sizes[0] / 128;
  int E = in_sizes[1] / 2;
  const int* src = ei;
  const int* dst = ei + E;

  const int G   = 256;                // blocks for the edge scatter (write locality)
  const int NBK = (N + 127) / 128;    // 391 buckets

  char* p = (char*)d_ws;
  size_t off = 0;
  auto take = [&](size_t bytes) -> void* {
    void* r = p + off;
    off += (bytes + 255) & ~(size_t)255;
    return r;
  };
  int*            gcur   = (int*)take((size_t)NBK * 4);
  int*            rowptr = (int*)take((size_t)N * 4);
  int*            rowend = (int*)take((size_t)N * 4);
  float*          dinv   = (float*)take((size_t)N * 4);
  unsigned*       e2     = (unsigned*)take((size_t)NBK * CAP * 4);
  int*            col    = (int*)take((size_t)NBK * CAP * 4);
  unsigned short* h      = (unsigned short*)take((size_t)N * 64 * 2);
  unsigned short* a      = (unsigned short*)take((size_t)N * 64 * 2);
  (void)ws_size; (void)n_in; (void)out_size;

  // graph build: 3 kernels (fixed-capacity buckets -> no count/scan pre-pass)
  k_init<<<(NBK + TPB - 1) / TPB, TPB, 0, stream>>>(gcur, NBK);
  k_bscatter<<<G, TPB, 0, stream>>>(src, dst, gcur, e2, E, NBK);
  k_build<<<NBK, TPB, 0, stream>>>(e2, gcur, rowptr, rowend, dinv, col, N);

  // network (H rows pre-scaled by dinv in the mm epilogues, bf16 storage)
  int gmm = (N + 63) / 64;
  k_mm<128, true><<<gmm, TPB, 0, stream>>>(x, w1, dinv, h, N);
  k_agg<false><<<(N + 3) / 4, TPB, 0, stream>>>(h, rowptr, rowend, col, dinv, b1, a,
                                                nullptr, nullptr, nullptr, nullptr,
                                                nullptr, N);
  k_mm<64, false><<<gmm, TPB, 0, stream>>>(a, w2, dinv, h, N);
  k_agg<true><<<4096, TPB, 0, stream>>>(h, rowptr, rowend, col, dinv, b2, nullptr,
                                        fw1, fb1, fw2, fb2, out, N);
}